// Round 6
// baseline (520.227 us; speedup 1.0000x reference)
//
#include <hip/hip_runtime.h>
#include <cstddef>
#include <cstdint>

#define D_MODEL 1024
#define D_STATE 8
#define D_INNER 1536
#define SEQ_L   2048
#define BATCH   4
#define MROWS   (BATCH * SEQ_L)   // 8192

// chunked scan: 16 chunks of 128, warmup 128 (|decay|<=0.55 -> err ~1e-32)
#define SCAN_CL 128
#define SCAN_W  128
#define SCAN_C  (SEQ_L / SCAN_CL)   // 16

typedef __attribute__((ext_vector_type(8))) short short8;
typedef __attribute__((ext_vector_type(4))) float f32x4;
typedef unsigned int u32;
typedef unsigned short u16;

__device__ __forceinline__ u16 bf_hi(float x) {            // truncate fp32 -> bf16
  return (u16)(__float_as_uint(x) >> 16);
}
__device__ __forceinline__ float bf_f(u16 h) {
  return __uint_as_float(((u32)h) << 16);
}
__device__ __forceinline__ void gload16(const void* g, void* l) {
  __builtin_amdgcn_global_load_lds((const __attribute__((address_space(1))) u32*)g,
                                   (__attribute__((address_space(3))) u32*)l, 16, 0, 0);
}
// LDS bank swizzle: physical 8-elem chunk = logical ^ swz4(row).
__device__ __forceinline__ int swz4(int row) { return (row ^ (row >> 2)) & 3; }

// ---------------------------------------------------------------- LayerNorm
// Plain fp32-out variant (used for LN-out -> d_out).
__global__ __launch_bounds__(256) void ln_kernel(
    const float* __restrict__ x, const float* __restrict__ g,
    const float* __restrict__ b, float* __restrict__ y)
{
  const int row = blockIdx.x;
  const int t = threadIdx.x;
  float4 v = reinterpret_cast<const float4*>(x + (size_t)row * D_MODEL)[t];
  float s  = v.x + v.y + v.z + v.w;
  float s2 = v.x * v.x + v.y * v.y + v.z * v.z + v.w * v.w;
  #pragma unroll
  for (int o = 32; o > 0; o >>= 1) {
    s  += __shfl_down(s, o);
    s2 += __shfl_down(s2, o);
  }
  __shared__ float ls[4], ls2[4];
  const int wid = t >> 6, lid = t & 63;
  if (lid == 0) { ls[wid] = s; ls2[wid] = s2; }
  __syncthreads();
  if (t == 0) {
    ls[0]  = ls[0] + ls[1] + ls[2] + ls[3];
    ls2[0] = ls2[0] + ls2[1] + ls2[2] + ls2[3];
  }
  __syncthreads();
  const float mean = ls[0] * (1.0f / D_MODEL);
  const float var  = ls2[0] * (1.0f / D_MODEL) - mean * mean;
  const float rstd = rsqrtf(var + 1e-5f);
  float4 gv = reinterpret_cast<const float4*>(g)[t];
  float4 bv = reinterpret_cast<const float4*>(b)[t];
  float4 o;
  o.x = (v.x - mean) * rstd * gv.x + bv.x;
  o.y = (v.y - mean) * rstd * gv.y + bv.y;
  o.z = (v.z - mean) * rstd * gv.z + bv.z;
  o.w = (v.w - mean) * rstd * gv.w + bv.w;
  reinterpret_cast<float4*>(y + (size_t)row * D_MODEL)[t] = o;
}

// LN-in variant: writes 2-term bf16 split planes (feeds GEMM1 directly).
__global__ __launch_bounds__(256) void ln_split_kernel(
    const float* __restrict__ x, const float* __restrict__ g,
    const float* __restrict__ b, u16* __restrict__ y0, u16* __restrict__ y1)
{
  const int row = blockIdx.x;
  const int t = threadIdx.x;
  float4 v = reinterpret_cast<const float4*>(x + (size_t)row * D_MODEL)[t];
  float s  = v.x + v.y + v.z + v.w;
  float s2 = v.x * v.x + v.y * v.y + v.z * v.z + v.w * v.w;
  #pragma unroll
  for (int o = 32; o > 0; o >>= 1) {
    s  += __shfl_down(s, o);
    s2 += __shfl_down(s2, o);
  }
  __shared__ float ls[4], ls2[4];
  const int wid = t >> 6, lid = t & 63;
  if (lid == 0) { ls[wid] = s; ls2[wid] = s2; }
  __syncthreads();
  if (t == 0) {
    ls[0]  = ls[0] + ls[1] + ls[2] + ls[3];
    ls2[0] = ls2[0] + ls2[1] + ls2[2] + ls2[3];
  }
  __syncthreads();
  const float mean = ls[0] * (1.0f / D_MODEL);
  const float var  = ls2[0] * (1.0f / D_MODEL) - mean * mean;
  const float rstd = rsqrtf(var + 1e-5f);
  float4 gv = reinterpret_cast<const float4*>(g)[t];
  float4 bv = reinterpret_cast<const float4*>(b)[t];
  float o[4];
  o[0] = (v.x - mean) * rstd * gv.x + bv.x;
  o[1] = (v.y - mean) * rstd * gv.y + bv.y;
  o[2] = (v.z - mean) * rstd * gv.z + bv.z;
  o[3] = (v.w - mean) * rstd * gv.w + bv.w;
  ushort4 h0, h1;
  u16 a, c;
  a = bf_hi(o[0]); c = bf_hi(o[0] - bf_f(a)); h0.x = a; h1.x = c;
  a = bf_hi(o[1]); c = bf_hi(o[1] - bf_f(a)); h0.y = a; h1.y = c;
  a = bf_hi(o[2]); c = bf_hi(o[2] - bf_f(a)); h0.z = a; h1.z = c;
  a = bf_hi(o[3]); c = bf_hi(o[3] - bf_f(a)); h0.w = a; h1.w = c;
  reinterpret_cast<ushort4*>(y0 + (size_t)row * D_MODEL)[t] = h0;
  reinterpret_cast<ushort4*>(y1 + (size_t)row * D_MODEL)[t] = h1;
}

// ------------------------------------------------- weight split kernel
__global__ __launch_bounds__(256) void wsplit2_kernel(
    const float* __restrict__ W, u16* __restrict__ a0, u16* __restrict__ a1, int n)
{
  int i = blockIdx.x * 256 + threadIdx.x;
  if (i >= n) return;
  float x = W[i];
  u16 h0 = bf_hi(x); float r1 = x - bf_f(h0);
  a0[i] = h0; a1[i] = bf_hi(r1);
}

// ---------------------------------------------------------------- GEMM
// out = clip(A @ B^T), A/B as 2-term bf16 splits, 3 MFMA combos.
// LDS-BW split strategy: A (activations) staged via global_load_lds into
// swizzled LDS (16 KB/iter); B (weights) fragments loaded DIRECTLY from
// global to registers (L1/L2-resident, reused by 64 consecutive m-blocks).
// This halves LDS traffic vs staging both sides (R5 was LDS-read-bound:
// measured MfmaUtil 46.6% == 233 MFMA cyc / 512 LDS cyc).
__global__ __launch_bounds__(256, 3) void gemm_kernel(
    const u16* __restrict__ A0, const u16* __restrict__ A1,
    const u16* __restrict__ B0, const u16* __restrict__ B1,
    float* __restrict__ out0, float* __restrict__ out1,
    int K, int split, int ld0, int ld1)
{
  __shared__ u16 As[2][128 * 32];
  const int t = threadIdx.x;
  const int wave = t >> 6, lane = t & 63;
  const int wr = wave >> 1, wc = wave & 1;
  const int q = lane >> 4, m16 = lane & 15;
  const int m0 = blockIdx.x * 128, n0 = blockIdx.y * 128;
  const int lr = lane >> 2;                    // staging row within 16-row group
  const int sch = (lane & 3) ^ swz4(lr);       // swizzled source chunk
  const int qsw = (q ^ swz4(m16)) * 8;         // swizzled fragment offset
  const u16* Asrc[2] = {A0, A1};

  // B fragment base: row n0 + wc*64 + nt*16 + m16, k offset q*8
  const u16* b0p = B0 + (size_t)(n0 + wc * 64 + m16) * K + q * 8;
  const u16* b1p = B1 + (size_t)(n0 + wc * 64 + m16) * K + q * 8;

  f32x4 acc[4][4];
  #pragma unroll
  for (int i = 0; i < 4; i++)
    #pragma unroll
    for (int j = 0; j < 4; j++) acc[i][j] = (f32x4)(0.0f);

  for (int kk = 0; kk < K; kk += 32) {
    __syncthreads();                           // prev iter's A reads done
    // stage A only: 2 terms x 2 row-groups per wave
    #pragma unroll
    for (int term = 0; term < 2; term++) {
      #pragma unroll
      for (int j = 0; j < 2; j++) {
        const u16* ga = Asrc[term] +
            (size_t)(m0 + wave * 32 + j * 16 + lr) * K + kk + sch * 8;
        gload16(ga, &As[term][(wave * 32 + j * 16) * 32]);
      }
    }
    // B fragments direct from global (no LDS) — issue early to hide latency
    short8 b0f[4], b1f[4];
    #pragma unroll
    for (int nt = 0; nt < 4; nt++)
      b0f[nt] = *reinterpret_cast<const short8*>(b0p + (size_t)(nt * 16) * K + kk);
    #pragma unroll
    for (int nt = 0; nt < 4; nt++)
      b1f[nt] = *reinterpret_cast<const short8*>(b1p + (size_t)(nt * 16) * K + kk);
    __syncthreads();                           // A staging drained
    short8 a0[4], a1[4];
    #pragma unroll
    for (int mt = 0; mt < 4; mt++)
      a0[mt] = *reinterpret_cast<const short8*>(
          &As[0][(wr * 64 + mt * 16 + m16) * 32 + qsw]);
    #pragma unroll
    for (int mt = 0; mt < 4; mt++)
      #pragma unroll
      for (int nt = 0; nt < 4; nt++)
        acc[mt][nt] = __builtin_amdgcn_mfma_f32_16x16x32_bf16(
            a0[mt], b0f[nt], acc[mt][nt], 0, 0, 0);
    #pragma unroll
    for (int mt = 0; mt < 4; mt++)
      #pragma unroll
      for (int nt = 0; nt < 4; nt++)
        acc[mt][nt] = __builtin_amdgcn_mfma_f32_16x16x32_bf16(
            a0[mt], b1f[nt], acc[mt][nt], 0, 0, 0);
    #pragma unroll
    for (int mt = 0; mt < 4; mt++)
      a1[mt] = *reinterpret_cast<const short8*>(
          &As[1][(wr * 64 + mt * 16 + m16) * 32 + qsw]);
    #pragma unroll
    for (int mt = 0; mt < 4; mt++)
      #pragma unroll
      for (int nt = 0; nt < 4; nt++)
        acc[mt][nt] = __builtin_amdgcn_mfma_f32_16x16x32_bf16(
            a1[mt], b0f[nt], acc[mt][nt], 0, 0, 0);
  }
  // epilogue: C/D layout col=lane&15, row=(lane>>4)*4+reg
  #pragma unroll
  for (int mt = 0; mt < 4; mt++) {
    #pragma unroll
    for (int nt = 0; nt < 4; nt++) {
      const int col = n0 + wc * 64 + nt * 16 + m16;
      #pragma unroll
      for (int r = 0; r < 4; r++) {
        const int row = m0 + wr * 64 + mt * 16 + q * 4 + r;
        float v = fminf(fmaxf(acc[mt][nt][r], -5.0f), 5.0f);
        if (col < split) out0[(size_t)row * ld0 + col] = v;
        else             out1[(size_t)row * ld1 + (col - split)] = v;
      }
    }
  }
}

// --------------------------------------------------------------- SSM scan
// Chunked: one thread per (chunk, b, i); warmup from h=0 (contraction,
// |decay| <= ~0.55 -> warmup error ~1e-32). Chunk 0 exact.
__global__ __launch_bounds__(256) void scan_kernel(
    const float* __restrict__ xssm, const float* __restrict__ gate,
    const float* __restrict__ A_log, const float* __restrict__ Bv,
    const float* __restrict__ Cv, u16* __restrict__ P0, u16* __restrict__ P1)
{
  const int gid = blockIdx.x * 256 + threadIdx.x;       // 0 .. 98303
  const int chunk = gid / (BATCH * D_INNER);            // 0..15
  const int rem = gid - chunk * (BATCH * D_INNER);
  const int b = rem / D_INNER;
  const int i = rem - b * D_INNER;

  float dec[D_STATE], bb[D_STATE], cc[D_STATE], h[D_STATE];
  #pragma unroll
  for (int s = 0; s < D_STATE; s++) {
    float al = A_log[i * D_STATE + s];
    al = fminf(fmaxf(al, -5.0f), 0.0f);
    float a = -__expf(al);
    a = fminf(fmaxf(a, -2.0f), -0.01f);
    dec[s] = a * 0.9f;
    bb[s]  = Bv[i * D_STATE + s] * 0.1f;
    cc[s]  = Cv[i * D_STATE + s];
    h[s]   = 0.0f;
  }

  const size_t base = (size_t)b * SEQ_L * D_INNER + i;
  const int tmain = chunk * SCAN_CL;
  const int tw = (tmain >= SCAN_W) ? (tmain - SCAN_W) : 0;

  for (int t0 = tw; t0 < tmain; t0 += 16) {
    float xv[16];
    #pragma unroll
    for (int j = 0; j < 16; j++)
      xv[j] = xssm[base + (size_t)(t0 + j) * D_INNER];
    #pragma unroll
    for (int j = 0; j < 16; j++) {
      const float x = xv[j];
      #pragma unroll
      for (int s = 0; s < D_STATE; s++) {
        h[s] = fmaf(h[s], dec[s], x * bb[s]);
        h[s] = fminf(fmaxf(h[s], -5.0f), 5.0f);
      }
    }
  }

  float xf[8], gf[8];
  #pragma unroll
  for (int j = 0; j < 8; j++) {
    xf[j] = xssm[base + (size_t)(tmain + j) * D_INNER];
    gf[j] = gate[base + (size_t)(tmain + j) * D_INNER];
  }
  for (int t0 = tmain; t0 < tmain + SCAN_CL; t0 += 8) {
    float xn[8], gn[8];
    if (t0 + 8 < tmain + SCAN_CL) {
      #pragma unroll
      for (int j = 0; j < 8; j++) {
        xn[j] = xssm[base + (size_t)(t0 + 8 + j) * D_INNER];
        gn[j] = gate[base + (size_t)(t0 + 8 + j) * D_INNER];
      }
    }
    #pragma unroll
    for (int j = 0; j < 8; j++) {
      const float x = xf[j];
      float y = 0.0f;
      #pragma unroll
      for (int s = 0; s < D_STATE; s++) {
        h[s] = fmaf(h[s], dec[s], x * bb[s]);
        h[s] = fminf(fmaxf(h[s], -5.0f), 5.0f);
        y = fmaf(h[s], cc[s], y);
      }
      y = fminf(fmaxf(y, -5.0f), 5.0f);
      const float e  = __expf(2.0f * gf[j]);
      const float th = __fdividef(e - 1.0f, e + 1.0f);
      const float p = y * th;
      const u16 h0 = bf_hi(p);
      const u16 h1 = bf_hi(p - bf_f(h0));
      P0[base + (size_t)(t0 + j) * D_INNER] = h0;
      P1[base + (size_t)(t0 + j) * D_INNER] = h1;
    }
    #pragma unroll
    for (int j = 0; j < 8; j++) { xf[j] = xn[j]; gf[j] = gn[j]; }
  }
}

// ---------------------------------------------------------------- launcher
extern "C" void kernel_launch(void* const* d_in, const int* in_sizes, int n_in,
                              void* d_out, int out_size, void* d_ws, size_t ws_size,
                              hipStream_t stream)
{
  const float* x        = (const float*)d_in[0];
  const float* W_in     = (const float*)d_in[1];
  const float* W_out    = (const float*)d_in[2];
  const float* A_log    = (const float*)d_in[3];
  const float* Bmat     = (const float*)d_in[4];
  const float* Cmat     = (const float*)d_in[5];
  const float* ln_in_g  = (const float*)d_in[6];
  const float* ln_in_b  = (const float*)d_in[7];
  const float* ln_out_g = (const float*)d_in[8];
  const float* ln_out_b = (const float*)d_in[9];
  float* out = (float*)d_out;

  // workspace (bytes):
  // [xssm 50331648][gate 50331648][xn0 16777216][xn1 16777216][B0 6291456]
  // [B1 6291456][gap][V0 3145728][V1 3145728]  total 159,383,552
  // P0/P1 (2x25165824) overlay xn0/xn1/B0/B1 (dead after gemm1);
  // outp overlays xssm (dead after scan).
  char* ws = (char*)d_ws;
  float* xssm = (float*)(ws);
  float* gate = (float*)(ws + 50331648);
  u16* xn0 = (u16*)(ws + 100663296);
  u16* xn1 = (u16*)(ws + 117440512);
  u16* B0  = (u16*)(ws + 134217728);
  u16* B1  = (u16*)(ws + 140509184);
  u16* V0  = (u16*)(ws + 153092096);
  u16* V1  = (u16*)(ws + 156237824);
  u16* P0  = (u16*)(ws + 100663296);
  u16* P1  = P0 + (size_t)MROWS * D_INNER;
  float* outp = xssm;

  // 0) split weights into 2-term bf16
  wsplit2_kernel<<<(2 * D_INNER * D_MODEL + 255) / 256, 256, 0, stream>>>(
      W_in, B0, B1, 2 * D_INNER * D_MODEL);
  wsplit2_kernel<<<(D_MODEL * D_INNER + 255) / 256, 256, 0, stream>>>(
      W_out, V0, V1, D_MODEL * D_INNER);

  // 1) LayerNorm-in -> 2-term bf16 planes
  ln_split_kernel<<<MROWS, 256, 0, stream>>>(x, ln_in_g, ln_in_b, xn0, xn1);

  // 2) x_proj = clip(xn @ W_in^T), split-store xssm/gate
  {
    dim3 grid(MROWS / 128, (2 * D_INNER) / 128);   // 64 x 24
    gemm_kernel<<<grid, 256, 0, stream>>>(xn0, xn1, B0, B1, xssm, gate,
                                          D_MODEL, D_INNER, D_INNER, D_INNER);
  }

  // 3) chunked SSM scan -> prod as 2-term bf16
  scan_kernel<<<(BATCH * D_INNER * SCAN_C) / 256, 256, 0, stream>>>(
      xssm, gate, A_log, Bmat, Cmat, P0, P1);

  // 4) out_pre = clip(prod @ W_out^T)
  {
    dim3 grid(MROWS / 128, D_MODEL / 128);          // 64 x 8
    gemm_kernel<<<grid, 256, 0, stream>>>(P0, P1, V0, V1, outp, outp,
                                          D_INNER, D_MODEL, D_MODEL, D_MODEL);
  }

  // 5) LayerNorm-out -> d_out
  ln_kernel<<<MROWS, 256, 0, stream>>>(outp, ln_out_g, ln_out_b, out);
}

// Round 7
// 386.410 us; speedup vs baseline: 1.3463x; 1.3463x over previous
//
#include <hip/hip_runtime.h>
#include <cstddef>
#include <cstdint>

#define D_MODEL 1024
#define D_STATE 8
#define D_INNER 1536
#define SEQ_L   2048
#define BATCH   4
#define MROWS   (BATCH * SEQ_L)   // 8192

// chunked scan: 16 chunks of 128, warmup 128 (|decay|<=0.55 -> err ~1e-32)
#define SCAN_CL 128
#define SCAN_W  128
#define SCAN_C  (SEQ_L / SCAN_CL)   // 16

typedef __attribute__((ext_vector_type(8))) short short8;
typedef __attribute__((ext_vector_type(4))) float f32x4;
typedef unsigned int u32;
typedef unsigned short u16;

__device__ __forceinline__ u16 bf_hi(float x) {            // truncate fp32 -> bf16
  return (u16)(__float_as_uint(x) >> 16);
}
__device__ __forceinline__ float bf_f(u16 h) {
  return __uint_as_float(((u32)h) << 16);
}
__device__ __forceinline__ void gload16(const void* g, void* l) {
  __builtin_amdgcn_global_load_lds((const __attribute__((address_space(1))) u32*)g,
                                   (__attribute__((address_space(3))) u32*)l, 16, 0, 0);
}
// LDS bank swizzle: physical 8-elem chunk = logical ^ swz4(row).
__device__ __forceinline__ int swz4(int row) { return (row ^ (row >> 2)) & 3; }

// ---------------------------------------------------------------- LayerNorm
// Plain fp32-out variant (used for LN-out -> d_out).
__global__ __launch_bounds__(256) void ln_kernel(
    const float* __restrict__ x, const float* __restrict__ g,
    const float* __restrict__ b, float* __restrict__ y)
{
  const int row = blockIdx.x;
  const int t = threadIdx.x;
  float4 v = reinterpret_cast<const float4*>(x + (size_t)row * D_MODEL)[t];
  float s  = v.x + v.y + v.z + v.w;
  float s2 = v.x * v.x + v.y * v.y + v.z * v.z + v.w * v.w;
  #pragma unroll
  for (int o = 32; o > 0; o >>= 1) {
    s  += __shfl_down(s, o);
    s2 += __shfl_down(s2, o);
  }
  __shared__ float ls[4], ls2[4];
  const int wid = t >> 6, lid = t & 63;
  if (lid == 0) { ls[wid] = s; ls2[wid] = s2; }
  __syncthreads();
  if (t == 0) {
    ls[0]  = ls[0] + ls[1] + ls[2] + ls[3];
    ls2[0] = ls2[0] + ls2[1] + ls2[2] + ls2[3];
  }
  __syncthreads();
  const float mean = ls[0] * (1.0f / D_MODEL);
  const float var  = ls2[0] * (1.0f / D_MODEL) - mean * mean;
  const float rstd = rsqrtf(var + 1e-5f);
  float4 gv = reinterpret_cast<const float4*>(g)[t];
  float4 bv = reinterpret_cast<const float4*>(b)[t];
  float4 o;
  o.x = (v.x - mean) * rstd * gv.x + bv.x;
  o.y = (v.y - mean) * rstd * gv.y + bv.y;
  o.z = (v.z - mean) * rstd * gv.z + bv.z;
  o.w = (v.w - mean) * rstd * gv.w + bv.w;
  reinterpret_cast<float4*>(y + (size_t)row * D_MODEL)[t] = o;
}

// LN-in variant: writes 2-term bf16 split planes (feeds GEMM1 directly).
__global__ __launch_bounds__(256) void ln_split_kernel(
    const float* __restrict__ x, const float* __restrict__ g,
    const float* __restrict__ b, u16* __restrict__ y0, u16* __restrict__ y1)
{
  const int row = blockIdx.x;
  const int t = threadIdx.x;
  float4 v = reinterpret_cast<const float4*>(x + (size_t)row * D_MODEL)[t];
  float s  = v.x + v.y + v.z + v.w;
  float s2 = v.x * v.x + v.y * v.y + v.z * v.z + v.w * v.w;
  #pragma unroll
  for (int o = 32; o > 0; o >>= 1) {
    s  += __shfl_down(s, o);
    s2 += __shfl_down(s2, o);
  }
  __shared__ float ls[4], ls2[4];
  const int wid = t >> 6, lid = t & 63;
  if (lid == 0) { ls[wid] = s; ls2[wid] = s2; }
  __syncthreads();
  if (t == 0) {
    ls[0]  = ls[0] + ls[1] + ls[2] + ls[3];
    ls2[0] = ls2[0] + ls2[1] + ls2[2] + ls2[3];
  }
  __syncthreads();
  const float mean = ls[0] * (1.0f / D_MODEL);
  const float var  = ls2[0] * (1.0f / D_MODEL) - mean * mean;
  const float rstd = rsqrtf(var + 1e-5f);
  float4 gv = reinterpret_cast<const float4*>(g)[t];
  float4 bv = reinterpret_cast<const float4*>(b)[t];
  float o[4];
  o[0] = (v.x - mean) * rstd * gv.x + bv.x;
  o[1] = (v.y - mean) * rstd * gv.y + bv.y;
  o[2] = (v.z - mean) * rstd * gv.z + bv.z;
  o[3] = (v.w - mean) * rstd * gv.w + bv.w;
  ushort4 h0, h1;
  u16 a, c;
  a = bf_hi(o[0]); c = bf_hi(o[0] - bf_f(a)); h0.x = a; h1.x = c;
  a = bf_hi(o[1]); c = bf_hi(o[1] - bf_f(a)); h0.y = a; h1.y = c;
  a = bf_hi(o[2]); c = bf_hi(o[2] - bf_f(a)); h0.z = a; h1.z = c;
  a = bf_hi(o[3]); c = bf_hi(o[3] - bf_f(a)); h0.w = a; h1.w = c;
  reinterpret_cast<ushort4*>(y0 + (size_t)row * D_MODEL)[t] = h0;
  reinterpret_cast<ushort4*>(y1 + (size_t)row * D_MODEL)[t] = h1;
}

// ------------------------------------------------- weight split kernel
// One launch handles both W_in (n1 elems -> a0/a1) and W_out (-> c0/c1).
__global__ __launch_bounds__(256) void wsplit_kernel(
    const float* __restrict__ W1, u16* __restrict__ a0, u16* __restrict__ a1,
    int n1, const float* __restrict__ W2, u16* __restrict__ c0,
    u16* __restrict__ c1, int n2)
{
  int i = blockIdx.x * 256 + threadIdx.x;
  if (i < n1) {
    float x = W1[i];
    u16 h0 = bf_hi(x);
    a0[i] = h0; a1[i] = bf_hi(x - bf_f(h0));
  } else if (i < n1 + n2) {
    int j = i - n1;
    float x = W2[j];
    u16 h0 = bf_hi(x);
    c0[j] = h0; c1[j] = bf_hi(x - bf_f(h0));
  }
}

// ---------------------------------------------------------------- GEMM
// out = clip(A @ B^T), A/B as 2-term bf16 splits, 3 MFMA combos
// (a0b0 + a0b1 + a1b0; rep error ~2^-16). Both operands staged via
// global_load_lds into swizzled LDS (m97 structure). Templated on MT
// (m-tiles per wave): block tile = (MT*32) x 128, wave tile (MT*16) x 64.
// MT=8 raises MFMA:LDS-read ratio 45.5% -> 62% (LDS-BW-bound regime,
// measured R5: MfmaUtil 46.6% == 233 MFMA cyc / 512 LDS cyc).
template <int MT>
__global__ __launch_bounds__(256, (MT == 8) ? 2 : 3) void gemm_kernel(
    const u16* __restrict__ A0, const u16* __restrict__ A1,
    const u16* __restrict__ B0, const u16* __restrict__ B1,
    float* __restrict__ out0, float* __restrict__ out1,
    int K, int split, int ld0, int ld1)
{
  constexpr int BR = MT * 32;                  // block rows
  __shared__ u16 As[2][BR * 32];
  __shared__ u16 Bs[2][128 * 32];
  const int t = threadIdx.x;
  const int wave = t >> 6, lane = t & 63;
  const int wr = wave >> 1, wc = wave & 1;
  const int q = lane >> 4, m16 = lane & 15;
  const int m0 = blockIdx.x * BR, n0 = blockIdx.y * 128;
  const int lr = lane >> 2;                    // staging row within 16-row group
  const int sch = (lane & 3) ^ swz4(lr);       // swizzled source chunk
  const int qsw = (q ^ swz4(m16)) * 8;         // swizzled fragment offset
  const u16* Asrc[2] = {A0, A1};
  const u16* Bsrc[2] = {B0, B1};

  f32x4 acc[MT][4];
  #pragma unroll
  for (int i = 0; i < MT; i++)
    #pragma unroll
    for (int j = 0; j < 4; j++) acc[i][j] = (f32x4)(0.0f);

  for (int kk = 0; kk < K; kk += 32) {
    __syncthreads();                           // prev iter's reads done
    #pragma unroll
    for (int term = 0; term < 2; term++) {
      #pragma unroll
      for (int j = 0; j < BR / 64; j++) {      // A: BR/64 row-groups per wave
        const u16* ga = Asrc[term] +
            (size_t)(m0 + wave * (BR / 4) + j * 16 + lr) * K + kk + sch * 8;
        gload16(ga, &As[term][(wave * (BR / 4) + j * 16) * 32]);
      }
      #pragma unroll
      for (int j = 0; j < 2; j++) {            // B: 2 row-groups per wave
        const u16* gb = Bsrc[term] +
            (size_t)(n0 + wave * 32 + j * 16 + lr) * K + kk + sch * 8;
        gload16(gb, &Bs[term][(wave * 32 + j * 16) * 32]);
      }
    }
    __syncthreads();                           // staging drained
    short8 b0f[4], b1f[4];
    #pragma unroll
    for (int nt = 0; nt < 4; nt++)
      b0f[nt] = *reinterpret_cast<const short8*>(
          &Bs[0][(wc * 64 + nt * 16 + m16) * 32 + qsw]);
    #pragma unroll
    for (int nt = 0; nt < 4; nt++)
      b1f[nt] = *reinterpret_cast<const short8*>(
          &Bs[1][(wc * 64 + nt * 16 + m16) * 32 + qsw]);
    #pragma unroll
    for (int mt = 0; mt < MT; mt++) {
      short8 a0 = *reinterpret_cast<const short8*>(
          &As[0][(wr * (MT * 16) + mt * 16 + m16) * 32 + qsw]);
      #pragma unroll
      for (int nt = 0; nt < 4; nt++)
        acc[mt][nt] = __builtin_amdgcn_mfma_f32_16x16x32_bf16(
            a0, b0f[nt], acc[mt][nt], 0, 0, 0);
      #pragma unroll
      for (int nt = 0; nt < 4; nt++)
        acc[mt][nt] = __builtin_amdgcn_mfma_f32_16x16x32_bf16(
            a0, b1f[nt], acc[mt][nt], 0, 0, 0);
    }
    #pragma unroll
    for (int mt = 0; mt < MT; mt++) {
      short8 a1 = *reinterpret_cast<const short8*>(
          &As[1][(wr * (MT * 16) + mt * 16 + m16) * 32 + qsw]);
      #pragma unroll
      for (int nt = 0; nt < 4; nt++)
        acc[mt][nt] = __builtin_amdgcn_mfma_f32_16x16x32_bf16(
            a1, b0f[nt], acc[mt][nt], 0, 0, 0);
    }
  }
  // epilogue: C/D layout col=lane&15, row=(lane>>4)*4+reg
  #pragma unroll
  for (int mt = 0; mt < MT; mt++) {
    #pragma unroll
    for (int nt = 0; nt < 4; nt++) {
      const int col = n0 + wc * 64 + nt * 16 + m16;
      #pragma unroll
      for (int r = 0; r < 4; r++) {
        const int row = m0 + wr * (MT * 16) + mt * 16 + q * 4 + r;
        float v = fminf(fmaxf(acc[mt][nt][r], -5.0f), 5.0f);
        if (col < split) out0[(size_t)row * ld0 + col] = v;
        else             out1[(size_t)row * ld1 + (col - split)] = v;
      }
    }
  }
}

// --------------------------------------------------------------- SSM scan
// Chunked: one thread per (chunk, b, i); warmup from h=0 (contraction,
// |decay| <= ~0.55 -> warmup error ~1e-32). Chunk 0 exact.
__global__ __launch_bounds__(256) void scan_kernel(
    const float* __restrict__ xssm, const float* __restrict__ gate,
    const float* __restrict__ A_log, const float* __restrict__ Bv,
    const float* __restrict__ Cv, u16* __restrict__ P0, u16* __restrict__ P1)
{
  const int gid = blockIdx.x * 256 + threadIdx.x;       // 0 .. 98303
  const int chunk = gid / (BATCH * D_INNER);            // 0..15
  const int rem = gid - chunk * (BATCH * D_INNER);
  const int b = rem / D_INNER;
  const int i = rem - b * D_INNER;

  float dec[D_STATE], bb[D_STATE], cc[D_STATE], h[D_STATE];
  #pragma unroll
  for (int s = 0; s < D_STATE; s++) {
    float al = A_log[i * D_STATE + s];
    al = fminf(fmaxf(al, -5.0f), 0.0f);
    float a = -__expf(al);
    a = fminf(fmaxf(a, -2.0f), -0.01f);
    dec[s] = a * 0.9f;
    bb[s]  = Bv[i * D_STATE + s] * 0.1f;
    cc[s]  = Cv[i * D_STATE + s];
    h[s]   = 0.0f;
  }

  const size_t base = (size_t)b * SEQ_L * D_INNER + i;
  const int tmain = chunk * SCAN_CL;
  const int tw = (tmain >= SCAN_W) ? (tmain - SCAN_W) : 0;

  for (int t0 = tw; t0 < tmain; t0 += 16) {
    float xv[16];
    #pragma unroll
    for (int j = 0; j < 16; j++)
      xv[j] = xssm[base + (size_t)(t0 + j) * D_INNER];
    #pragma unroll
    for (int j = 0; j < 16; j++) {
      const float x = xv[j];
      #pragma unroll
      for (int s = 0; s < D_STATE; s++) {
        h[s] = fmaf(h[s], dec[s], x * bb[s]);
        h[s] = fminf(fmaxf(h[s], -5.0f), 5.0f);
      }
    }
  }

  float xf[8], gf[8];
  #pragma unroll
  for (int j = 0; j < 8; j++) {
    xf[j] = xssm[base + (size_t)(tmain + j) * D_INNER];
    gf[j] = gate[base + (size_t)(tmain + j) * D_INNER];
  }
  for (int t0 = tmain; t0 < tmain + SCAN_CL; t0 += 8) {
    float xn[8], gn[8];
    if (t0 + 8 < tmain + SCAN_CL) {
      #pragma unroll
      for (int j = 0; j < 8; j++) {
        xn[j] = xssm[base + (size_t)(t0 + 8 + j) * D_INNER];
        gn[j] = gate[base + (size_t)(t0 + 8 + j) * D_INNER];
      }
    }
    #pragma unroll
    for (int j = 0; j < 8; j++) {
      const float x = xf[j];
      float y = 0.0f;
      #pragma unroll
      for (int s = 0; s < D_STATE; s++) {
        h[s] = fmaf(h[s], dec[s], x * bb[s]);
        h[s] = fminf(fmaxf(h[s], -5.0f), 5.0f);
        y = fmaf(h[s], cc[s], y);
      }
      y = fminf(fmaxf(y, -5.0f), 5.0f);
      const float e  = __expf(2.0f * gf[j]);
      const float th = __fdividef(e - 1.0f, e + 1.0f);
      const float p = y * th;
      const u16 h0 = bf_hi(p);
      const u16 h1 = bf_hi(p - bf_f(h0));
      P0[base + (size_t)(t0 + j) * D_INNER] = h0;
      P1[base + (size_t)(t0 + j) * D_INNER] = h1;
    }
    #pragma unroll
    for (int j = 0; j < 8; j++) { xf[j] = xn[j]; gf[j] = gn[j]; }
  }
}

// ---------------------------------------------------------------- launcher
extern "C" void kernel_launch(void* const* d_in, const int* in_sizes, int n_in,
                              void* d_out, int out_size, void* d_ws, size_t ws_size,
                              hipStream_t stream)
{
  const float* x        = (const float*)d_in[0];
  const float* W_in     = (const float*)d_in[1];
  const float* W_out    = (const float*)d_in[2];
  const float* A_log    = (const float*)d_in[3];
  const float* Bmat     = (const float*)d_in[4];
  const float* Cmat     = (const float*)d_in[5];
  const float* ln_in_g  = (const float*)d_in[6];
  const float* ln_in_b  = (const float*)d_in[7];
  const float* ln_out_g = (const float*)d_in[8];
  const float* ln_out_b = (const float*)d_in[9];
  float* out = (float*)d_out;

  // workspace (bytes):
  // [xssm 50331648][gate 50331648][xn0 16777216][xn1 16777216][B0 6291456]
  // [B1 6291456][gap][V0 3145728][V1 3145728]  total 159,383,552
  // P0/P1 (2x25165824) overlay xn0/xn1/B0/B1 (dead after gemm1);
  // outp overlays xssm (dead after scan).
  char* ws = (char*)d_ws;
  float* xssm = (float*)(ws);
  float* gate = (float*)(ws + 50331648);
  u16* xn0 = (u16*)(ws + 100663296);
  u16* xn1 = (u16*)(ws + 117440512);
  u16* B0  = (u16*)(ws + 134217728);
  u16* B1  = (u16*)(ws + 140509184);
  u16* V0  = (u16*)(ws + 153092096);
  u16* V1  = (u16*)(ws + 156237824);
  u16* P0  = (u16*)(ws + 100663296);
  u16* P1  = P0 + (size_t)MROWS * D_INNER;
  float* outp = xssm;

  // 0) split both weight matrices into 2-term bf16 (single launch)
  {
    const int n1 = 2 * D_INNER * D_MODEL;      // W_in
    const int n2 = D_MODEL * D_INNER;          // W_out
    wsplit_kernel<<<(n1 + n2 + 255) / 256, 256, 0, stream>>>(
        W_in, B0, B1, n1, W_out, V0, V1, n2);
  }

  // 1) LayerNorm-in -> 2-term bf16 planes
  ln_split_kernel<<<MROWS, 256, 0, stream>>>(x, ln_in_g, ln_in_b, xn0, xn1);

  // 2) x_proj = clip(xn @ W_in^T), split-store xssm/gate  (MT=8: 256x128)
  {
    dim3 grid(MROWS / 256, (2 * D_INNER) / 128);   // 32 x 24
    gemm_kernel<8><<<grid, 256, 0, stream>>>(xn0, xn1, B0, B1, xssm, gate,
                                             D_MODEL, D_INNER, D_INNER, D_INNER);
  }

  // 3) chunked SSM scan -> prod as 2-term bf16
  scan_kernel<<<(BATCH * D_INNER * SCAN_C) / 256, 256, 0, stream>>>(
      xssm, gate, A_log, Bmat, Cmat, P0, P1);

  // 4) out_pre = clip(prod @ W_out^T)  (MT=4: 128x128, 512 blocks, 3/CU)
  {
    dim3 grid(MROWS / 128, D_MODEL / 128);          // 64 x 8
    gemm_kernel<4><<<grid, 256, 0, stream>>>(P0, P1, V0, V1, outp, outp,
                                             D_INNER, D_MODEL, D_MODEL, D_MODEL);
  }

  // 5) LayerNorm-out -> d_out
  ln_kernel<<<MROWS, 256, 0, stream>>>(outp, ln_out_g, ln_out_b, out);
}

// Round 8
// 351.222 us; speedup vs baseline: 1.4812x; 1.1002x over previous
//
#include <hip/hip_runtime.h>
#include <cstddef>
#include <cstdint>

#define D_MODEL 1024
#define D_STATE 8
#define D_INNER 1536
#define SEQ_L   2048
#define BATCH   4
#define MROWS   (BATCH * SEQ_L)   // 8192

// chunked scan: 16 chunks of 128, warmup 128 (|decay|<=0.55 -> err ~1e-32)
#define SCAN_CL 128
#define SCAN_W  128
#define SCAN_C  (SEQ_L / SCAN_CL)   // 16

typedef __attribute__((ext_vector_type(8))) short short8;
typedef __attribute__((ext_vector_type(4))) float f32x4;
typedef unsigned int u32;
typedef unsigned short u16;

__device__ __forceinline__ u16 bf_hi(float x) {            // truncate fp32 -> bf16
  return (u16)(__float_as_uint(x) >> 16);
}
__device__ __forceinline__ float bf_f(u16 h) {
  return __uint_as_float(((u32)h) << 16);
}
__device__ __forceinline__ void gload16(const void* g, void* l) {
  __builtin_amdgcn_global_load_lds((const __attribute__((address_space(1))) u32*)g,
                                   (__attribute__((address_space(3))) u32*)l, 16, 0, 0);
}
// LDS bank swizzle: physical 8-elem chunk = logical ^ swz4(row).
__device__ __forceinline__ int swz4(int row) { return (row ^ (row >> 2)) & 3; }

// ---------------------------------------------------------------- LayerNorm
// Plain fp32-out variant (used for LN-out -> d_out).
__global__ __launch_bounds__(256) void ln_kernel(
    const float* __restrict__ x, const float* __restrict__ g,
    const float* __restrict__ b, float* __restrict__ y)
{
  const int row = blockIdx.x;
  const int t = threadIdx.x;
  float4 v = reinterpret_cast<const float4*>(x + (size_t)row * D_MODEL)[t];
  float s  = v.x + v.y + v.z + v.w;
  float s2 = v.x * v.x + v.y * v.y + v.z * v.z + v.w * v.w;
  #pragma unroll
  for (int o = 32; o > 0; o >>= 1) {
    s  += __shfl_down(s, o);
    s2 += __shfl_down(s2, o);
  }
  __shared__ float ls[4], ls2[4];
  const int wid = t >> 6, lid = t & 63;
  if (lid == 0) { ls[wid] = s; ls2[wid] = s2; }
  __syncthreads();
  if (t == 0) {
    ls[0]  = ls[0] + ls[1] + ls[2] + ls[3];
    ls2[0] = ls2[0] + ls2[1] + ls2[2] + ls2[3];
  }
  __syncthreads();
  const float mean = ls[0] * (1.0f / D_MODEL);
  const float var  = ls2[0] * (1.0f / D_MODEL) - mean * mean;
  const float rstd = rsqrtf(var + 1e-5f);
  float4 gv = reinterpret_cast<const float4*>(g)[t];
  float4 bv = reinterpret_cast<const float4*>(b)[t];
  float4 o;
  o.x = (v.x - mean) * rstd * gv.x + bv.x;
  o.y = (v.y - mean) * rstd * gv.y + bv.y;
  o.z = (v.z - mean) * rstd * gv.z + bv.z;
  o.w = (v.w - mean) * rstd * gv.w + bv.w;
  reinterpret_cast<float4*>(y + (size_t)row * D_MODEL)[t] = o;
}

// LN-in variant: writes 2-term bf16 split planes (feeds GEMM1 directly).
__global__ __launch_bounds__(256) void ln_split_kernel(
    const float* __restrict__ x, const float* __restrict__ g,
    const float* __restrict__ b, u16* __restrict__ y0, u16* __restrict__ y1)
{
  const int row = blockIdx.x;
  const int t = threadIdx.x;
  float4 v = reinterpret_cast<const float4*>(x + (size_t)row * D_MODEL)[t];
  float s  = v.x + v.y + v.z + v.w;
  float s2 = v.x * v.x + v.y * v.y + v.z * v.z + v.w * v.w;
  #pragma unroll
  for (int o = 32; o > 0; o >>= 1) {
    s  += __shfl_down(s, o);
    s2 += __shfl_down(s2, o);
  }
  __shared__ float ls[4], ls2[4];
  const int wid = t >> 6, lid = t & 63;
  if (lid == 0) { ls[wid] = s; ls2[wid] = s2; }
  __syncthreads();
  if (t == 0) {
    ls[0]  = ls[0] + ls[1] + ls[2] + ls[3];
    ls2[0] = ls2[0] + ls2[1] + ls2[2] + ls2[3];
  }
  __syncthreads();
  const float mean = ls[0] * (1.0f / D_MODEL);
  const float var  = ls2[0] * (1.0f / D_MODEL) - mean * mean;
  const float rstd = rsqrtf(var + 1e-5f);
  float4 gv = reinterpret_cast<const float4*>(g)[t];
  float4 bv = reinterpret_cast<const float4*>(b)[t];
  float o[4];
  o[0] = (v.x - mean) * rstd * gv.x + bv.x;
  o[1] = (v.y - mean) * rstd * gv.y + bv.y;
  o[2] = (v.z - mean) * rstd * gv.z + bv.z;
  o[3] = (v.w - mean) * rstd * gv.w + bv.w;
  ushort4 h0, h1;
  u16 a, c;
  a = bf_hi(o[0]); c = bf_hi(o[0] - bf_f(a)); h0.x = a; h1.x = c;
  a = bf_hi(o[1]); c = bf_hi(o[1] - bf_f(a)); h0.y = a; h1.y = c;
  a = bf_hi(o[2]); c = bf_hi(o[2] - bf_f(a)); h0.z = a; h1.z = c;
  a = bf_hi(o[3]); c = bf_hi(o[3] - bf_f(a)); h0.w = a; h1.w = c;
  reinterpret_cast<ushort4*>(y0 + (size_t)row * D_MODEL)[t] = h0;
  reinterpret_cast<ushort4*>(y1 + (size_t)row * D_MODEL)[t] = h1;
}

// ------------------------------------------------- weight split kernel
// One launch handles both W_in (n1 elems -> a0/a1) and W_out (-> c0/c1).
__global__ __launch_bounds__(256) void wsplit_kernel(
    const float* __restrict__ W1, u16* __restrict__ a0, u16* __restrict__ a1,
    int n1, const float* __restrict__ W2, u16* __restrict__ c0,
    u16* __restrict__ c1, int n2)
{
  int i = blockIdx.x * 256 + threadIdx.x;
  if (i < n1) {
    float x = W1[i];
    u16 h0 = bf_hi(x);
    a0[i] = h0; a1[i] = bf_hi(x - bf_f(h0));
  } else if (i < n1 + n2) {
    int j = i - n1;
    float x = W2[j];
    u16 h0 = bf_hi(x);
    c0[j] = h0; c1[j] = bf_hi(x - bf_f(h0));
  }
}

// ---------------------------------------------------------------- GEMM
// out = clip(A @ B^T), A/B as 2-term bf16 splits. R5 structure (best
// measured: MT=4, 128x128 tile, BK=32, 3 blocks/CU, both operands via
// swizzled global_load_lds LDS).
// Precision is column-dependent: blocks fully inside col < lowprec_cols
// use 1 MFMA combo (pure bf16 a0b0 — their output feeds the SSM scan,
// which attenuates input error by ~1e-4) and stage only the 0-term
// planes; other blocks use 3 combos (a0b0+a0b1+a1b0, rel err ~2^-16).
__global__ __launch_bounds__(256, 3) void gemm_kernel(
    const u16* __restrict__ A0, const u16* __restrict__ A1,
    const u16* __restrict__ B0, const u16* __restrict__ B1,
    float* __restrict__ out0, float* __restrict__ out1,
    int K, int split, int ld0, int ld1, int lowprec_cols)
{
  __shared__ u16 As[2][128 * 32];
  __shared__ u16 Bs[2][128 * 32];
  const int t = threadIdx.x;
  const int wave = t >> 6, lane = t & 63;
  const int wr = wave >> 1, wc = wave & 1;
  const int q = lane >> 4, m16 = lane & 15;
  const int m0 = blockIdx.x * 128, n0 = blockIdx.y * 128;
  const bool three = (n0 + 128 > lowprec_cols);   // 3-combo block?
  const int lr = lane >> 2;                    // staging row within 16-row group
  const int sch = (lane & 3) ^ swz4(lr);       // swizzled source chunk
  const int qsw = (q ^ swz4(m16)) * 8;         // swizzled fragment offset

  f32x4 acc[4][4];
  #pragma unroll
  for (int i = 0; i < 4; i++)
    #pragma unroll
    for (int j = 0; j < 4; j++) acc[i][j] = (f32x4)(0.0f);

  for (int kk = 0; kk < K; kk += 32) {
    __syncthreads();                           // prev iter's reads done
    #pragma unroll
    for (int j = 0; j < 2; j++) {              // term-0 planes (always)
      const u16* ga = A0 + (size_t)(m0 + wave * 32 + j * 16 + lr) * K + kk + sch * 8;
      gload16(ga, &As[0][(wave * 32 + j * 16) * 32]);
      const u16* gb = B0 + (size_t)(n0 + wave * 32 + j * 16 + lr) * K + kk + sch * 8;
      gload16(gb, &Bs[0][(wave * 32 + j * 16) * 32]);
    }
    if (three) {
      #pragma unroll
      for (int j = 0; j < 2; j++) {            // term-1 planes
        const u16* ga = A1 + (size_t)(m0 + wave * 32 + j * 16 + lr) * K + kk + sch * 8;
        gload16(ga, &As[1][(wave * 32 + j * 16) * 32]);
        const u16* gb = B1 + (size_t)(n0 + wave * 32 + j * 16 + lr) * K + kk + sch * 8;
        gload16(gb, &Bs[1][(wave * 32 + j * 16) * 32]);
      }
    }
    __syncthreads();                           // staging drained
    short8 a0[4], b0f[4];
    #pragma unroll
    for (int mt = 0; mt < 4; mt++)
      a0[mt] = *reinterpret_cast<const short8*>(
          &As[0][(wr * 64 + mt * 16 + m16) * 32 + qsw]);
    #pragma unroll
    for (int nt = 0; nt < 4; nt++)
      b0f[nt] = *reinterpret_cast<const short8*>(
          &Bs[0][(wc * 64 + nt * 16 + m16) * 32 + qsw]);
    #pragma unroll
    for (int mt = 0; mt < 4; mt++)
      #pragma unroll
      for (int nt = 0; nt < 4; nt++)
        acc[mt][nt] = __builtin_amdgcn_mfma_f32_16x16x32_bf16(
            a0[mt], b0f[nt], acc[mt][nt], 0, 0, 0);
    if (three) {
      short8 b1f[4];
      #pragma unroll
      for (int nt = 0; nt < 4; nt++)
        b1f[nt] = *reinterpret_cast<const short8*>(
            &Bs[1][(wc * 64 + nt * 16 + m16) * 32 + qsw]);
      #pragma unroll
      for (int mt = 0; mt < 4; mt++)
        #pragma unroll
        for (int nt = 0; nt < 4; nt++)
          acc[mt][nt] = __builtin_amdgcn_mfma_f32_16x16x32_bf16(
              a0[mt], b1f[nt], acc[mt][nt], 0, 0, 0);
      short8 a1[4];
      #pragma unroll
      for (int mt = 0; mt < 4; mt++)
        a1[mt] = *reinterpret_cast<const short8*>(
            &As[1][(wr * 64 + mt * 16 + m16) * 32 + qsw]);
      #pragma unroll
      for (int mt = 0; mt < 4; mt++)
        #pragma unroll
        for (int nt = 0; nt < 4; nt++)
          acc[mt][nt] = __builtin_amdgcn_mfma_f32_16x16x32_bf16(
              a1[mt], b0f[nt], acc[mt][nt], 0, 0, 0);
    }
  }
  // epilogue: C/D layout col=lane&15, row=(lane>>4)*4+reg
  #pragma unroll
  for (int mt = 0; mt < 4; mt++) {
    #pragma unroll
    for (int nt = 0; nt < 4; nt++) {
      const int col = n0 + wc * 64 + nt * 16 + m16;
      #pragma unroll
      for (int r = 0; r < 4; r++) {
        const int row = m0 + wr * 64 + mt * 16 + q * 4 + r;
        float v = fminf(fmaxf(acc[mt][nt][r], -5.0f), 5.0f);
        if (col < split) out0[(size_t)row * ld0 + col] = v;
        else             out1[(size_t)row * ld1 + (col - split)] = v;
      }
    }
  }
}

// --------------------------------------------------------------- SSM scan
// Chunked: one thread per (chunk, b, i); warmup from h=0 (contraction,
// |decay| <= ~0.55 -> warmup error ~1e-32). Chunk 0 exact.
__global__ __launch_bounds__(256) void scan_kernel(
    const float* __restrict__ xssm, const float* __restrict__ gate,
    const float* __restrict__ A_log, const float* __restrict__ Bv,
    const float* __restrict__ Cv, u16* __restrict__ P0, u16* __restrict__ P1)
{
  const int gid = blockIdx.x * 256 + threadIdx.x;       // 0 .. 98303
  const int chunk = gid / (BATCH * D_INNER);            // 0..15
  const int rem = gid - chunk * (BATCH * D_INNER);
  const int b = rem / D_INNER;
  const int i = rem - b * D_INNER;

  float dec[D_STATE], bb[D_STATE], cc[D_STATE], h[D_STATE];
  #pragma unroll
  for (int s = 0; s < D_STATE; s++) {
    float al = A_log[i * D_STATE + s];
    al = fminf(fmaxf(al, -5.0f), 0.0f);
    float a = -__expf(al);
    a = fminf(fmaxf(a, -2.0f), -0.01f);
    dec[s] = a * 0.9f;
    bb[s]  = Bv[i * D_STATE + s] * 0.1f;
    cc[s]  = Cv[i * D_STATE + s];
    h[s]   = 0.0f;
  }

  const size_t base = (size_t)b * SEQ_L * D_INNER + i;
  const int tmain = chunk * SCAN_CL;
  const int tw = (tmain >= SCAN_W) ? (tmain - SCAN_W) : 0;

  for (int t0 = tw; t0 < tmain; t0 += 16) {
    float xv[16];
    #pragma unroll
    for (int j = 0; j < 16; j++)
      xv[j] = xssm[base + (size_t)(t0 + j) * D_INNER];
    #pragma unroll
    for (int j = 0; j < 16; j++) {
      const float x = xv[j];
      #pragma unroll
      for (int s = 0; s < D_STATE; s++) {
        h[s] = fmaf(h[s], dec[s], x * bb[s]);
        h[s] = fminf(fmaxf(h[s], -5.0f), 5.0f);
      }
    }
  }

  float xf[8], gf[8];
  #pragma unroll
  for (int j = 0; j < 8; j++) {
    xf[j] = xssm[base + (size_t)(tmain + j) * D_INNER];
    gf[j] = gate[base + (size_t)(tmain + j) * D_INNER];
  }
  for (int t0 = tmain; t0 < tmain + SCAN_CL; t0 += 8) {
    float xn[8], gn[8];
    if (t0 + 8 < tmain + SCAN_CL) {
      #pragma unroll
      for (int j = 0; j < 8; j++) {
        xn[j] = xssm[base + (size_t)(t0 + 8 + j) * D_INNER];
        gn[j] = gate[base + (size_t)(t0 + 8 + j) * D_INNER];
      }
    }
    #pragma unroll
    for (int j = 0; j < 8; j++) {
      const float x = xf[j];
      float y = 0.0f;
      #pragma unroll
      for (int s = 0; s < D_STATE; s++) {
        h[s] = fmaf(h[s], dec[s], x * bb[s]);
        h[s] = fminf(fmaxf(h[s], -5.0f), 5.0f);
        y = fmaf(h[s], cc[s], y);
      }
      y = fminf(fmaxf(y, -5.0f), 5.0f);
      const float e  = __expf(2.0f * gf[j]);
      const float th = __fdividef(e - 1.0f, e + 1.0f);
      const float p = y * th;
      const u16 h0 = bf_hi(p);
      const u16 h1 = bf_hi(p - bf_f(h0));
      P0[base + (size_t)(t0 + j) * D_INNER] = h0;
      P1[base + (size_t)(t0 + j) * D_INNER] = h1;
    }
    #pragma unroll
    for (int j = 0; j < 8; j++) { xf[j] = xn[j]; gf[j] = gn[j]; }
  }
}

// ---------------------------------------------------------------- launcher
extern "C" void kernel_launch(void* const* d_in, const int* in_sizes, int n_in,
                              void* d_out, int out_size, void* d_ws, size_t ws_size,
                              hipStream_t stream)
{
  const float* x        = (const float*)d_in[0];
  const float* W_in     = (const float*)d_in[1];
  const float* W_out    = (const float*)d_in[2];
  const float* A_log    = (const float*)d_in[3];
  const float* Bmat     = (const float*)d_in[4];
  const float* Cmat     = (const float*)d_in[5];
  const float* ln_in_g  = (const float*)d_in[6];
  const float* ln_in_b  = (const float*)d_in[7];
  const float* ln_out_g = (const float*)d_in[8];
  const float* ln_out_b = (const float*)d_in[9];
  float* out = (float*)d_out;

  // workspace (bytes):
  // [xssm 50331648][gate 50331648][xn0 16777216][xn1 16777216][B0 6291456]
  // [B1 6291456][gap][V0 3145728][V1 3145728]  total 159,383,552
  // P0/P1 (2x25165824) overlay xn0/xn1/B0/B1 (dead after gemm1);
  // outp overlays xssm (dead after scan).
  char* ws = (char*)d_ws;
  float* xssm = (float*)(ws);
  float* gate = (float*)(ws + 50331648);
  u16* xn0 = (u16*)(ws + 100663296);
  u16* xn1 = (u16*)(ws + 117440512);
  u16* B0  = (u16*)(ws + 134217728);
  u16* B1  = (u16*)(ws + 140509184);
  u16* V0  = (u16*)(ws + 153092096);
  u16* V1  = (u16*)(ws + 156237824);
  u16* P0  = (u16*)(ws + 100663296);
  u16* P1  = P0 + (size_t)MROWS * D_INNER;
  float* outp = xssm;

  // 0) split both weight matrices into 2-term bf16 (single launch)
  {
    const int n1 = 2 * D_INNER * D_MODEL;      // W_in
    const int n2 = D_MODEL * D_INNER;          // W_out
    wsplit_kernel<<<(n1 + n2 + 255) / 256, 256, 0, stream>>>(
        W_in, B0, B1, n1, W_out, V0, V1, n2);
  }

  // 1) LayerNorm-in -> 2-term bf16 planes
  ln_split_kernel<<<MROWS, 256, 0, stream>>>(x, ln_in_g, ln_in_b, xn0, xn1);

  // 2) x_proj = clip(xn @ W_in^T), split-store xssm/gate.
  //    Columns < 1536 (x_ssm half) use 1-combo pure bf16 (scan attenuates
  //    their error ~1e-4x); gate half uses 3 combos.
  {
    dim3 grid(MROWS / 128, (2 * D_INNER) / 128);   // 64 x 24
    gemm_kernel<<<grid, 256, 0, stream>>>(xn0, xn1, B0, B1, xssm, gate,
                                          D_MODEL, D_INNER, D_INNER, D_INNER,
                                          D_INNER /* lowprec: x_ssm half */);
  }

  // 3) chunked SSM scan -> prod as 2-term bf16
  scan_kernel<<<(BATCH * D_INNER * SCAN_C) / 256, 256, 0, stream>>>(
      xssm, gate, A_log, Bmat, Cmat, P0, P1);

  // 4) out_pre = clip(prod @ W_out^T) — full 3-combo precision
  {
    dim3 grid(MROWS / 128, D_MODEL / 128);          // 64 x 8
    gemm_kernel<<<grid, 256, 0, stream>>>(P0, P1, V0, V1, outp, outp,
                                          D_INNER, D_MODEL, D_MODEL, D_MODEL,
                                          0 /* all high-precision */);
  }

  // 5) LayerNorm-out -> d_out
  ln_kernel<<<MROWS, 256, 0, stream>>>(outp, ln_out_g, ln_out_b, out);
}